// Round 2
// baseline (401.646 us; speedup 1.0000x reference)
//
#include <hip/hip_runtime.h>

// R1Pool: guide-driven quadrant pooling.
// out[b,c,i,j] = x[b,c, argmax_{i'<=i, j'<=j} guide]  (ties: max j', then max i')
// Implemented as a running 2D prefix "rightmost-max" scan carrying (guide_val, x_val)
// so no index gather is needed. One 64-lane wave per (b,c) plane, 4 cols/lane.

constexpr int Hh = 256;
constexpr int Ww = 256;

__global__ __launch_bounds__(64)
void r1pool_kernel(const float* __restrict__ xg, const float* __restrict__ gg,
                   float* __restrict__ og) {
    const int plane = blockIdx.x;
    const int lane  = threadIdx.x;          // 0..63
    const size_t base = (size_t)plane * (size_t)(Hh * Ww);
    const float* __restrict__ gp = gg + base;
    const float* __restrict__ xp = xg + base;
    float*       __restrict__ op = og + base;
    const int col = lane << 2;              // 4 contiguous columns per lane

    // Per-column running quadrant max (value) and the x at its argmax.
    float m0 = -INFINITY, m1 = -INFINITY, m2 = -INFINITY, m3 = -INFINITY;
    float q0 = 0.f, q1 = 0.f, q2 = 0.f, q3 = 0.f;

    // 4-deep row prefetch (static indices only: unrolled by 4).
    float4 gb[4], xb[4];
#pragma unroll
    for (int u = 0; u < 4; ++u) {
        gb[u] = *reinterpret_cast<const float4*>(gp + u * Ww + col);
        xb[u] = *reinterpret_cast<const float4*>(xp + u * Ww + col);
    }

#pragma unroll 1
    for (int i = 0; i < Hh; i += 4) {
#pragma unroll
        for (int u = 0; u < 4; ++u) {
            const int row = i + u;
            const float4 gc = gb[u];
            const float4 xc = xb[u];
            const int pre = row + 4;
            if (pre < Hh) {   // wave-uniform branch
                gb[u] = *reinterpret_cast<const float4*>(gp + pre * Ww + col);
                xb[u] = *reinterpret_cast<const float4*>(xp + pre * Ww + col);
            }

            // Column combine: current row wins ties (g >= m).
            bool t0 = (gc.x >= m0), t1 = (gc.y >= m1), t2 = (gc.z >= m2), t3 = (gc.w >= m3);
            float v0 = t0 ? gc.x : m0, w0 = t0 ? xc.x : q0;
            float v1 = t1 ? gc.y : m1, w1 = t1 ? xc.y : q1;
            float v2 = t2 ? gc.z : m2, w2 = t2 ? xc.z : q2;
            float v3 = t3 ? gc.w : m3, w3 = t3 ? xc.w : q3;

            // Local inclusive scan over the 4 columns (later column wins ties).
            bool a1 = (v1 >= v0);
            float s1v = a1 ? v1 : v0, s1x = a1 ? w1 : w0;
            bool a2 = (v2 >= s1v);
            float s2v = a2 ? v2 : s1v, s2x = a2 ? w2 : s1x;
            bool a3 = (v3 >= s2v);
            float s3v = a3 ? v3 : s2v, s3x = a3 ? w3 : s2x;

            // Wave inclusive scan of per-lane aggregates (self/higher-lane wins ties,
            // so only replace when the left prefix is STRICTLY greater).
            float av = s3v, ax = s3x;
#pragma unroll
            for (int d = 1; d < 64; d <<= 1) {
                float nv = __shfl_up(av, (unsigned)d, 64);
                float nx = __shfl_up(ax, (unsigned)d, 64);
                if (lane >= d && nv > av) { av = nv; ax = nx; }
            }
            // Exclusive prefix (from lane-1's inclusive result).
            float ev = __shfl_up(av, 1u, 64);
            float ex = __shfl_up(ax, 1u, 64);
            if (lane == 0) { ev = -INFINITY; ex = 0.f; }

            // Final combine per column: local scan value wins ties vs left prefix.
            bool f0 = (v0  >= ev), f1 = (s1v >= ev), f2 = (s2v >= ev);
            m0 = f0 ? v0  : ev;  q0 = f0 ? w0  : ex;
            m1 = f1 ? s1v : ev;  q1 = f1 ? s1x : ex;
            m2 = f2 ? s2v : ev;  q2 = f2 ? s2x : ex;
            m3 = av;             q3 = ax;   // inclusive scan at this lane == full prefix

            float4 o; o.x = q0; o.y = q1; o.z = q2; o.w = q3;
            *reinterpret_cast<float4*>(op + row * Ww + col) = o;
        }
    }
}

extern "C" void kernel_launch(void* const* d_in, const int* in_sizes, int n_in,
                              void* d_out, int out_size, void* d_ws, size_t ws_size,
                              hipStream_t stream) {
    const float* x = (const float*)d_in[0];
    const float* g = (const float*)d_in[1];
    float* out = (float*)d_out;
    const int n = in_sizes[0];
    const int planes = n / (Hh * Ww);       // 8*64 = 512
    r1pool_kernel<<<dim3(planes), dim3(64), 0, stream>>>(x, g, out);
}

// Round 5
// 335.267 us; speedup vs baseline: 1.1980x; 1.1980x over previous
//
#include <hip/hip_runtime.h>

// R1Pool: guide-driven quadrant pooling — EXACT reference recurrence.
// Per row: v[j] = (g[i,j] >= carry[j]) ? (g,x) : carry   (current row wins ties)
//          carry = inclusive rightmost-wins max-scan of v;  out = carry.x
// The tie semantics are path-dependent (carry propagation), so the recurrence
// cannot be decoupled across rows (R4 failure: tied record cells are common
// because jax normals have only 2^23 atoms). Structure identical to the
// verified-exact R2 kernel; the wave scan is re-implemented with DPP
// (row_shr / row_bcast at VALU latency) instead of 7 dependent ds_bpermute
// __shfl_up steps — the R2 bottleneck (1880 cyc/row, VALUBusy 6.5%, HBM 17%).
// One 64-lane wave per (b,c) plane, 4 contiguous cols/lane, 8-row prefetch.

constexpr int Hh = 256;
constexpr int Ww = 256;
constexpr int RB = 8;     // prefetch depth in rows

// DPP move: result = src from DPP-selected lane, or `oldv` where the source
// lane is invalid (row boundary) — old = -inf is the scan identity.
template<int CTRL>
__device__ __forceinline__ float dpp_f(float oldv, float src) {
    return __int_as_float(__builtin_amdgcn_update_dpp(
        __float_as_int(oldv), __float_as_int(src), CTRL, 0xF, 0xF, false));
}
// DPP ctrl encodings (GFX9+): row_shr:N = 0x110+N, row_bcast15 = 0x142,
// row_bcast31 = 0x143. Row ops never cross 16-lane row boundaries.

__global__ __launch_bounds__(64)
void r1pool_kernel(const float* __restrict__ xg, const float* __restrict__ gg,
                   float* __restrict__ og) {
    const int plane = blockIdx.x;
    const int lane  = threadIdx.x;          // 0..63
    const size_t base = (size_t)plane * (size_t)(Hh * Ww);
    const float* __restrict__ gp = gg + base;
    const float* __restrict__ xp = xg + base;
    float*       __restrict__ op = og + base;
    const int col = lane << 2;              // 4 contiguous columns per lane
    const float NI = -INFINITY;

    const bool fix15 = (lane == 16) || (lane == 48);  // exclusive-shift row fixups
    const bool fix31 = (lane == 32);

    // Carry = reference scan state S[j] per owned column: (value, x at argmax).
    float m[4], q[4];
#pragma unroll
    for (int c = 0; c < 4; ++c) { m[c] = NI; q[c] = 0.f; }

    // 8-row register prefetch (static indices; unrolled).
    float4 gb[RB], xb[RB];
#pragma unroll
    for (int u = 0; u < RB; ++u) {
        gb[u] = *reinterpret_cast<const float4*>(gp + u * Ww + col);
        xb[u] = *reinterpret_cast<const float4*>(xp + u * Ww + col);
    }

#pragma unroll 1
    for (int i0 = 0; i0 < Hh; i0 += RB) {
        const bool more = (i0 + RB < Hh);   // wave-uniform
#pragma unroll
        for (int u = 0; u < RB; ++u) {
            const int row = i0 + u;
            const float gc[4] = {gb[u].x, gb[u].y, gb[u].z, gb[u].w};
            const float xc[4] = {xb[u].x, xb[u].y, xb[u].z, xb[u].w};
            if (more) {   // refill slot u for row+RB — 8-row lead hides HBM latency
                gb[u] = *reinterpret_cast<const float4*>(gp + (row + RB) * Ww + col);
                xb[u] = *reinterpret_cast<const float4*>(xp + (row + RB) * Ww + col);
            }

            // Column step: current row wins ties vs carried quadrant max.
            float cv[4], cx[4];
#pragma unroll
            for (int c = 0; c < 4; ++c) {
                const bool t = (gc[c] >= m[c]);
                cv[c] = t ? gc[c] : m[c];
                cx[c] = t ? xc[c] : q[c];
            }
            // Lane-local inclusive scan over 4 columns (rightmost wins ties).
#pragma unroll
            for (int c = 1; c < 4; ++c) {
                const bool t = (cv[c] >= cv[c - 1]);
                cv[c] = t ? cv[c] : cv[c - 1];
                cx[c] = t ? cx[c] : cx[c - 1];
            }

            // Wave-wide inclusive pair scan of lane aggregates via DPP.
            // Left operand arrives from lower lanes -> replace only on STRICT
            // greater (self/rightmost wins ties) — matches reference hscan.
            float av = cv[3], ax = cx[3];
            {
                float lv, lx; bool t;
                lv = dpp_f<0x111>(NI, av); lx = dpp_f<0x111>(NI, ax);   // shr 1
                t = lv > av; av = t ? lv : av; ax = t ? lx : ax;
                lv = dpp_f<0x112>(NI, av); lx = dpp_f<0x112>(NI, ax);   // shr 2
                t = lv > av; av = t ? lv : av; ax = t ? lx : ax;
                lv = dpp_f<0x114>(NI, av); lx = dpp_f<0x114>(NI, ax);   // shr 4
                t = lv > av; av = t ? lv : av; ax = t ? lx : ax;
                lv = dpp_f<0x118>(NI, av); lx = dpp_f<0x118>(NI, ax);   // shr 8
                t = lv > av; av = t ? lv : av; ax = t ? lx : ax;
                lv = dpp_f<0x142>(NI, av); lx = dpp_f<0x142>(NI, ax);   // bcast15
                t = lv > av; av = t ? lv : av; ax = t ? lx : ax;
                lv = dpp_f<0x143>(NI, av); lx = dpp_f<0x143>(NI, ax);   // bcast31
                t = lv > av; av = t ? lv : av; ax = t ? lx : ax;
            }

            // Exclusive prefix: shift inclusive result right by one lane.
            // row_shr:1 leaves lanes 0/16/32/48 at -inf; lanes 16,48 take the
            // previous row's lane-15/47 inclusive (bcast15), lane 32 takes
            // lane 31's (bcast31); lane 0 keeps -inf.
            float ev = dpp_f<0x111>(NI, av);
            float ex = dpp_f<0x111>(NI, ax);
            {
                const float b15v = dpp_f<0x142>(NI, av);
                const float b15x = dpp_f<0x142>(NI, ax);
                const float b31v = dpp_f<0x143>(NI, av);
                const float b31x = dpp_f<0x143>(NI, ax);
                if (fix15) { ev = b15v; ex = b15x; }
                if (fix31) { ev = b31v; ex = b31x; }
            }

            // Final combine per column: local prefix wins ties vs left prefix.
            // This IS the reference carry S_i[j]; its x is the output.
#pragma unroll
            for (int c = 0; c < 4; ++c) {
                const bool t = (cv[c] >= ev);
                m[c] = t ? cv[c] : ev;
                q[c] = t ? cx[c] : ex;
            }
            float4 o; o.x = q[0]; o.y = q[1]; o.z = q[2]; o.w = q[3];
            *reinterpret_cast<float4*>(op + row * Ww + col) = o;
        }
    }
}

extern "C" void kernel_launch(void* const* d_in, const int* in_sizes, int n_in,
                              void* d_out, int out_size, void* d_ws, size_t ws_size,
                              hipStream_t stream) {
    const float* x = (const float*)d_in[0];
    const float* g = (const float*)d_in[1];
    float* out = (float*)d_out;
    const int n = in_sizes[0];
    const int planes = n / (Hh * Ww);       // 8*64 = 512
    r1pool_kernel<<<dim3(planes), dim3(64), 0, stream>>>(x, g, out);
}

// Round 8
// 320.513 us; speedup vs baseline: 1.2531x; 1.0460x over previous
//
#include <hip/hip_runtime.h>

// R1Pool: guide-driven quadrant pooling — EXACT reference recurrence.
// Per row: v[j] = (g[i,j] >= carry[j]) ? (g,x) : carry   (current row wins ties)
//          carry = inclusive rightmost-wins max-scan of v;  out = carry.x
// Tie semantics are path-dependent (carry propagation), so rows cannot be
// decoupled (R4 failure: jax normals have ~2^23 atoms -> tied records common).
// Scan = DPP (row_shr / row_bcast) pair-scan, verified exact in R5.
//
// R5 post-mortem: VGPR_Count=56 proved the compiler sank my 8-row register
// prefetch (needs 64 VGPRs) to point-of-use -> ~900 cyc exposed HBM latency
// per row batch in the serial chain (1340 cyc/row, VALU 16%, HBM 23%).
// R6: LDS double-buffered staging via global_load_lds(width=16) with a
// counted-wait pipeline: drain prev stage (vmcnt 0), bulk ds_read batch to
// regs, THEN issue next stage so its HBM latency hides under this batch's
// ~3.5k cyc of compute. One 64-lane wave per (b,c) plane, 4 cols/lane.

constexpr int Hh = 256;
constexpr int Ww = 256;
constexpr int RB = 8;     // rows per batch

template<int CTRL>
__device__ __forceinline__ float dpp_f(float oldv, float src) {
    return __int_as_float(__builtin_amdgcn_update_dpp(
        __float_as_int(oldv), __float_as_int(src), CTRL, 0xF, 0xF, false));
}
// DPP ctrls: row_shr:N = 0x110+N, row_bcast15 = 0x142, row_bcast31 = 0x143.

typedef const __attribute__((address_space(1))) unsigned int* gas_p;
typedef __attribute__((address_space(3))) unsigned int* las_p;

__global__ __launch_bounds__(64)
void r1pool_kernel(const float* __restrict__ xg, const float* __restrict__ gg,
                   float* __restrict__ og) {
    __shared__ float lds[2][2][RB][Ww];     // 2 buf x {g,x} x 8 rows x 256 = 32 KB

    const int plane = blockIdx.x;
    const int lane  = threadIdx.x;          // 0..63
    const size_t base = (size_t)plane * (size_t)(Hh * Ww);
    const float* __restrict__ gp = gg + base;
    const float* __restrict__ xp = xg + base;
    float*       __restrict__ op = og + base;
    const int col = lane << 2;              // 4 contiguous columns per lane
    const float NI = -INFINITY;

    const bool fix15 = (lane == 16) || (lane == 48);
    const bool fix31 = (lane == 32);

    // Async stage of one 8-row batch into LDS buffer `buf`.
    // LDS dest is wave-uniform base + lane*16 (HW rule) == linear row layout;
    // global src is per-lane (row start + lane*16B). Both match col = lane*4.
#define STAGE(buf, i0base)                                                     \
    {                                                                          \
        _Pragma("unroll")                                                      \
        for (int u = 0; u < RB; ++u) {                                         \
            __builtin_amdgcn_global_load_lds(                                  \
                (gas_p)(gp + ((i0base) + u) * Ww + col),                       \
                (las_p)&lds[buf][0][u][0], 16, 0, 0);                          \
            __builtin_amdgcn_global_load_lds(                                  \
                (gas_p)(xp + ((i0base) + u) * Ww + col),                       \
                (las_p)&lds[buf][1][u][0], 16, 0, 0);                          \
        }                                                                      \
    }

    // Carry = reference scan state per owned column: (value, x at argmax).
    float m[4], q[4];
#pragma unroll
    for (int c = 0; c < 4; ++c) { m[c] = NI; q[c] = 0.f; }

    STAGE(0, 0);                            // prologue fill

#pragma unroll 1
    for (int i0 = 0; i0 < Hh; i0 += RB) {
        const int cur = (i0 >> 3) & 1;

        // Previous stage (buffer `cur`) complete. Only that stage's 16 loads
        // are outstanding here, so vmcnt(0) == counted wait, no over-drain.
        asm volatile("s_waitcnt vmcnt(0)" ::: "memory");

        // Bulk LDS -> regs for the whole batch (16x ds_read_b128; compiler
        // inserts fine-grained lgkmcnt before first use of each).
        float4 gb[RB], xb[RB];
#pragma unroll
        for (int u = 0; u < RB; ++u) {
            gb[u] = *reinterpret_cast<const float4*>(&lds[cur][0][u][col]);
            xb[u] = *reinterpret_cast<const float4*>(&lds[cur][1][u][col]);
        }

        // Now issue next batch's stage into the other buffer; its ~900 cyc
        // HBM latency hides under this batch's ~3.5k cyc of scan compute.
        if (i0 + RB < Hh) STAGE(cur ^ 1, i0 + RB);

#pragma unroll
        for (int u = 0; u < RB; ++u) {
            const int row = i0 + u;
            const float gc[4] = {gb[u].x, gb[u].y, gb[u].z, gb[u].w};
            const float xc[4] = {xb[u].x, xb[u].y, xb[u].z, xb[u].w};

            // Column step: current row wins ties vs carried quadrant max.
            float cv[4], cx[4];
#pragma unroll
            for (int c = 0; c < 4; ++c) {
                const bool t = (gc[c] >= m[c]);
                cv[c] = t ? gc[c] : m[c];
                cx[c] = t ? xc[c] : q[c];
            }
            // Lane-local inclusive scan over 4 columns (rightmost wins ties).
#pragma unroll
            for (int c = 1; c < 4; ++c) {
                const bool t = (cv[c] >= cv[c - 1]);
                cv[c] = t ? cv[c] : cv[c - 1];
                cx[c] = t ? cx[c] : cx[c - 1];
            }

            // Wave-wide inclusive pair scan via DPP; left prefix arrives from
            // lower lanes -> replace only on STRICT greater (rightmost wins).
            float av = cv[3], ax = cx[3];
            {
                float lv, lx; bool t;
                lv = dpp_f<0x111>(NI, av); lx = dpp_f<0x111>(NI, ax);   // shr 1
                t = lv > av; av = t ? lv : av; ax = t ? lx : ax;
                lv = dpp_f<0x112>(NI, av); lx = dpp_f<0x112>(NI, ax);   // shr 2
                t = lv > av; av = t ? lv : av; ax = t ? lx : ax;
                lv = dpp_f<0x114>(NI, av); lx = dpp_f<0x114>(NI, ax);   // shr 4
                t = lv > av; av = t ? lv : av; ax = t ? lx : ax;
                lv = dpp_f<0x118>(NI, av); lx = dpp_f<0x118>(NI, ax);   // shr 8
                t = lv > av; av = t ? lv : av; ax = t ? lx : ax;
                lv = dpp_f<0x142>(NI, av); lx = dpp_f<0x142>(NI, ax);   // bcast15
                t = lv > av; av = t ? lv : av; ax = t ? lx : ax;
                lv = dpp_f<0x143>(NI, av); lx = dpp_f<0x143>(NI, ax);   // bcast31
                t = lv > av; av = t ? lv : av; ax = t ? lx : ax;
            }

            // Exclusive prefix: shift inclusive right one lane; patch the
            // 16-lane row boundaries (shr never crosses them).
            float ev = dpp_f<0x111>(NI, av);
            float ex = dpp_f<0x111>(NI, ax);
            {
                const float b15v = dpp_f<0x142>(NI, av);
                const float b15x = dpp_f<0x142>(NI, ax);
                const float b31v = dpp_f<0x143>(NI, av);
                const float b31x = dpp_f<0x143>(NI, ax);
                if (fix15) { ev = b15v; ex = b15x; }
                if (fix31) { ev = b31v; ex = b31x; }
            }

            // Final combine per column -> reference carry S_i[j]; x is output.
#pragma unroll
            for (int c = 0; c < 4; ++c) {
                const bool t = (cv[c] >= ev);
                m[c] = t ? cv[c] : ev;
                q[c] = t ? cx[c] : ex;
            }
            float4 o; o.x = q[0]; o.y = q[1]; o.z = q[2]; o.w = q[3];
            *reinterpret_cast<float4*>(op + row * Ww + col) = o;
        }
    }
#undef STAGE
}

extern "C" void kernel_launch(void* const* d_in, const int* in_sizes, int n_in,
                              void* d_out, int out_size, void* d_ws, size_t ws_size,
                              hipStream_t stream) {
    const float* x = (const float*)d_in[0];
    const float* g = (const float*)d_in[1];
    float* out = (float*)d_out;
    const int n = in_sizes[0];
    const int planes = n / (Hh * Ww);       // 8*64 = 512
    r1pool_kernel<<<dim3(planes), dim3(64), 0, stream>>>(x, g, out);
}